// Round 20
// baseline (713.418 us; speedup 1.0000x reference)
//
#include <hip/hip_runtime.h>
#include <hip/hip_fp16.h>
#include <stdint.h>

#define BB 512
#define NN 200
#define FF 16
#define WW 256
#define DD 5
#define LATD 128
#define ALPHA 0.2f
#define M_CAP 57344   // E[sum lengths]=51456, +4.5 sigma

// ws layout (bytes)
#define WS_CNT  0         // int ticket counter
#define WS_NV   64        // int nv[512]
#define WS_RS   2112      // int rstart[512]
#define WS_PERM 4160      // int perm[512] (rank -> batch, Nv descending)
#define WS_WSF  6208      // half wsf[229376] (Gmid frags l*65536; GammaL @196608)
#define WS_H    464960    // half h[M_CAP][256]

typedef _Float16 f16x8 __attribute__((ext_vector_type(8)));
typedef float f32x4 __attribute__((ext_vector_type(4)));

__device__ __forceinline__ float lrelu(float v) { return v >= 0.f ? v : ALPHA * v; }
__device__ __forceinline__ unsigned pk2(float a, float b) {
    __half2 h = __floats2half2_rn(a, b);
    return *reinterpret_cast<unsigned*>(&h);
}
// swizzled stage byte offset: row-major 512B rows, XOR row bits into bits 4-6
__device__ __forceinline__ unsigned swz(int rl, int cb) {
    return (unsigned)(rl * 512 + cb) ^ (unsigned)((rl & 7) << 4);
}

// ---- K1: blocks [0,512): per-batch Nv; blocks [512,624): weight fragment packing ----
__global__ __launch_bounds__(256) void k1_kernel(const float* __restrict__ x,
                                                 const float* __restrict__ Gmid,
                                                 const float* __restrict__ GammaL,
                                                 _Float16* __restrict__ wsf,
                                                 int* __restrict__ nv) {
    const int tid = threadIdx.x;
    if (blockIdx.x < BB) {
        __shared__ int wavecnt[4];
        const int lane = tid & 63, w = tid >> 6;
        const float* xb = x + (size_t)blockIdx.x * NN * FF;
        bool flag = false;
        if (tid < NN) {
            const float4* xr = (const float4*)(xb + tid * FF);
            float4 v0 = xr[0], v1 = xr[1], v2 = xr[2], v3 = xr[3];
            flag = (v0.x != 0.f) | (v0.y != 0.f) | (v0.z != 0.f) | (v0.w != 0.f) |
                   (v1.x != 0.f) | (v1.y != 0.f) | (v1.z != 0.f) | (v1.w != 0.f) |
                   (v2.x != 0.f) | (v2.y != 0.f) | (v2.z != 0.f) | (v2.w != 0.f) |
                   (v3.x != 0.f) | (v3.y != 0.f) | (v3.z != 0.f) | (v3.w != 0.f);
        }
        unsigned long long bal = __ballot(flag);
        if (lane == 0) wavecnt[w] = __popcll(bal);
        __syncthreads();
        if (tid == 0) nv[blockIdx.x] = wavecnt[0] + wavecnt[1] + wavecnt[2] + wavecnt[3];
        return;
    }
    int t = (int)(blockIdx.x - BB) * 256 + tid;
    if (t < 24576) {                       // Gmid: 3 x (K=256 -> 32 octets) x (N=256)
        int layer = t / 8192, r = t % 8192;
        int a = r / 256, n = r % 256;
        const float* G = Gmid + (size_t)layer * 65536;
        f16x8 v;
#pragma unroll
        for (int j = 0; j < 8; ++j) v[j] = (_Float16)G[(8 * a + j) * 256 + n];
        int chunk = a >> 2, g = a & 3, cf = n >> 4, ln = (n & 15) + 16 * g;
        *(f16x8*)(wsf + (size_t)layer * 65536 + ((size_t)(chunk * 16 + cf) * 64 + ln) * 8) = v;
    } else if (t < 28672) {                // GammaL: K=256, N=128
        int r = t - 24576;
        int a = r / 128, n = r % 128;
        f16x8 v;
#pragma unroll
        for (int j = 0; j < 8; ++j) v[j] = (_Float16)GammaL[(8 * a + j) * 128 + n];
        int chunk = a >> 2, g = a & 3, cf = n >> 4, ln = (n & 15) + 16 * g;
        *(f16x8*)(wsf + 196608 + ((size_t)(chunk * 8 + cf) * 64 + ln) * 8) = v;
    }
}

// ---- K2: prefix over Nv -> rstart; rank by Nv desc -> perm; zero ticket ----
__global__ __launch_bounds__(512) void prefix_kernel(const int* __restrict__ nv,
                                                     int* __restrict__ rstart,
                                                     int* __restrict__ perm,
                                                     int* __restrict__ cnt) {
    __shared__ int s[512];
    __shared__ int nvs[512];
    const int t = threadIdx.x;
    if (t == 0) cnt[0] = 0;
    int my = nv[t];
    s[t] = my;
    nvs[t] = my;
    __syncthreads();
    // rank (descending Nv, tie-break by index)
    int rank = 0;
    for (int b2 = 0; b2 < 512; ++b2) {
        int o = nvs[b2];
        rank += (o > my) || (o == my && b2 < t);
    }
    perm[rank] = t;
    for (int off = 1; off < 512; off <<= 1) {
        int v = (t >= off) ? s[t - off] : 0;
        __syncthreads();
        s[t] += v;
        __syncthreads();
    }
    rstart[t] = s[t] - my;
}

struct __align__(16) FusedLds {
    union U {
        struct { float xl[NN * FF]; float g0[FF * WW]; } p;  // 29184 B, prologue/l0 only
        unsigned short stage[128 * 256];                     // 65536 B swizzled resident tile
    } u;
    float mred[512];       // reduction scratch
    float csred[8][256];   // per-wave colsum partials
    float csl[256];        // colsum / pooled
    float mpj_s[256];
    float ybuf[2][256];    // MLP ping-pong
    float xmean[FF];
    int wavecnt[8];
    int tkt;
};

// fs -> csl[0..NC)
template <int NC>
__device__ __forceinline__ void colsum_finish(FusedLds& S, const float* fs,
                                              int tid, int lane, int w) {
    constexpr int CPW = NC / 64;
    const int cg = w & 3, cl = lane & 15;
#pragma unroll
    for (int u = 0; u < CPW; ++u) {
        float s = fs[u];
        s += __shfl_xor(s, 16);
        s += __shfl_xor(s, 32);
        if (lane < 16) S.csred[w][(cg * CPW + u) * 16 + cl] = s;
    }
    __syncthreads();
    if (tid < NC) {
        const int cgb = tid / (16 * CPW);
        S.csl[tid] = S.csred[cgb][tid] + S.csred[4 + cgb][tid];
    }
    __syncthreads();
}

// MULTI-PASS layer: in-place on global h rows, direct L2 gather.
// No mid-pass barrier (wave-ownership argument; see round-18 comment).
template <int NC>
__device__ __forceinline__ void gemm_layer(FusedLds& S, const _Float16* __restrict__ wf,
                                           unsigned short* __restrict__ hb,
                                           int rs0, int Nv, int tid, int lane, int w) {
    constexpr int CPW = NC / 64;
    const int rg = w >> 2, cg = w & 3, cl = lane & 15, g = lane >> 4;
    const int RF = (Nv + 15) >> 4;                 // <= 13
    float fs[CPW];
#pragma unroll
    for (int u = 0; u < CPW; ++u) fs[u] = 0.f;
    const _Float16* hf = (const _Float16*)hb;
    for (int p0 = 0; p0 < RF; p0 += 8) {
        f32x4 acc[4][CPW];
#pragma unroll
        for (int i = 0; i < 4; ++i)
#pragma unroll
            for (int u = 0; u < CPW; ++u)
#pragma unroll
                for (int j = 0; j < 4; ++j) acc[i][u][j] = 0.f;
        bool act[4];
        int rowc[4];
#pragma unroll
        for (int i = 0; i < 4; ++i) {
            const int rf = p0 + rg + 2 * i;
            act[i] = rf < RF;
            int row = rs0 + rf * 16 + cl;
            rowc[i] = row < rs0 + Nv ? row : rs0 + Nv - 1;  // clamp; outputs guarded
        }
#pragma unroll
        for (int c = 0; c < 8; ++c) {
            f16x8 bfr[CPW];
#pragma unroll
            for (int u = 0; u < CPW; ++u)
                bfr[u] = *(const f16x8*)(wf + ((size_t)(c * (NC / 16) + cg * CPW + u) * 64 + lane) * 8);
#pragma unroll
            for (int i = 0; i < 4; ++i) {
                if (act[i]) {
                    f16x8 af = *(const f16x8*)(hf + (size_t)rowc[i] * 256 + c * 32 + g * 8);
#pragma unroll
                    for (int u = 0; u < CPW; ++u)
                        acc[i][u] = __builtin_amdgcn_mfma_f32_16x16x32_f16(af, bfr[u], acc[i][u], 0, 0, 0);
                }
            }
        }
#pragma unroll
        for (int i = 0; i < 4; ++i) {
            if (act[i]) {
                const int rbase = rs0 + (p0 + rg + 2 * i) * 16 + 4 * g;
#pragma unroll
                for (int j = 0; j < 4; ++j) {
                    const int row = rbase + j;
                    if (row < rs0 + Nv) {
#pragma unroll
                        for (int u = 0; u < CPW; ++u) {
                            const int col = (cg * CPW + u) * 16 + cl;
                            float o = lrelu(acc[i][u][j] - S.mpj_s[col]);
                            *((_Float16*)hb + (size_t)row * 256 + col) = (_Float16)o;
                            fs[u] += o;
                        }
                    }
                }
            }
        }
    }
    colsum_finish<NC>(S, fs, tid, lane, w);
}

// coalesced load of vrows 512B-rows from hb[rs0..] into swizzled stage
__device__ __forceinline__ void tile_load(FusedLds& S, const unsigned short* __restrict__ hb,
                                          int rs0, int vrows, int tid) {
#pragma unroll
    for (int v = 0; v < 8; ++v) {
        const int rl = v * 16 + (tid >> 5);
        if (rl < vrows) {
            const int cb = (tid & 31) * 16;
            *(uint4*)((char*)S.u.stage + swz(rl, cb)) =
                *(const uint4*)((const char*)hb + ((size_t)(rs0 + rl)) * 512 + cb);
        }
    }
}

// RESIDENT layer (Nv<=128): LDS-only, in-place on stage tile. No mid barrier.
template <int NC>
__device__ __forceinline__ void eq_tile_res(FusedLds& S, const _Float16* __restrict__ wf,
                                            int vrows, int tid, int lane, int w) {
    constexpr int CPW = NC / 64;
    const int rg = w >> 2, cg = w & 3, cl = lane & 15, g = lane >> 4;
    const int RFL = (vrows + 15) >> 4;     // <= 8
    float fs[CPW];
#pragma unroll
    for (int u = 0; u < CPW; ++u) fs[u] = 0.f;
    f32x4 acc[4][CPW];
#pragma unroll
    for (int i = 0; i < 4; ++i)
#pragma unroll
        for (int u = 0; u < CPW; ++u)
#pragma unroll
            for (int j = 0; j < 4; ++j) acc[i][u][j] = 0.f;
    bool act[4];
    int rll[4];
#pragma unroll
    for (int i = 0; i < 4; ++i) {
        const int rf = rg + 2 * i;
        act[i] = rf < RFL;
        int rl = rf * 16 + cl;
        rll[i] = rl < vrows ? rl : vrows - 1;   // clamp; outputs guarded
    }
#pragma unroll
    for (int c = 0; c < 8; ++c) {
        f16x8 bfr[CPW];
#pragma unroll
        for (int u = 0; u < CPW; ++u)
            bfr[u] = *(const f16x8*)(wf + ((size_t)(c * (NC / 16) + cg * CPW + u) * 64 + lane) * 8);
#pragma unroll
        for (int i = 0; i < 4; ++i) {
            if (act[i]) {
                f16x8 af = *(const f16x8*)((const char*)S.u.stage + swz(rll[i], c * 64 + (g << 4)));
#pragma unroll
                for (int u = 0; u < CPW; ++u)
                    acc[i][u] = __builtin_amdgcn_mfma_f32_16x16x32_f16(af, bfr[u], acc[i][u], 0, 0, 0);
            }
        }
    }
#pragma unroll
    for (int i = 0; i < 4; ++i) {
        if (act[i]) {
            const int rlb = (rg + 2 * i) * 16 + 4 * g;
#pragma unroll
            for (int j = 0; j < 4; ++j) {
                const int rl = rlb + j;
                const bool valid = rl < vrows;
#pragma unroll
                for (int u = 0; u < CPW; ++u) {
                    const int col = (cg * CPW + u) * 16 + cl;
                    float o = lrelu(acc[i][u][j] - S.mpj_s[col]);
                    *(_Float16*)((char*)S.u.stage + swz(rl, col * 2)) = (_Float16)o;
                    if (valid) fs[u] += o;
                }
            }
        }
    }
    colsum_finish<NC>(S, fs, tid, lane, w);
}

// mpj_s[0..256) = (csl @ Lmid[l]) * invNv
__device__ __forceinline__ void mproj_mid(FusedLds& S, const float* __restrict__ Lmid,
                                          int l, float invNv, int tid) {
    const float* L = Lmid + (size_t)l * 65536;
    const int c = tid & 255, seg = tid >> 8;
    float a = 0.f;
    const float* Lp = L + (size_t)seg * 128 * 256 + c;
    const float* mh = S.csl + seg * 128;
#pragma unroll 8
    for (int k = 0; k < 128; ++k) a = fmaf(mh[k], Lp[(size_t)k * 256], a);
    S.mred[seg * 256 + c] = a;
    __syncthreads();
    if (tid < 256) S.mpj_s[tid] = (S.mred[tid] + S.mred[256 + tid]) * invNv;
    __syncthreads();
}

// mpj_s[0..128) = (csl @ LambdaL) * invNv
__device__ __forceinline__ void mproj_last(FusedLds& S, const float* __restrict__ LambdaL,
                                           float invNv, int tid) {
    const int c = tid & 127, seg = tid >> 7;
    float a = 0.f;
    const float* Lp = LambdaL + (size_t)seg * 64 * 128 + c;
    const float* mh = S.csl + seg * 64;
#pragma unroll 8
    for (int k = 0; k < 64; ++k) a = fmaf(mh[k], Lp[(size_t)k * 128], a);
    S.mred[seg * 128 + c] = a;
    __syncthreads();
    if (tid < 128)
        S.mpj_s[tid] = (S.mred[tid] + S.mred[128 + tid] + S.mred[256 + tid] + S.mred[384 + tid]) * invNv;
    __syncthreads();
}

// ---- FUSED persistent: blocks pull batches (Nv-descending) via atomic ticket ----
__global__ __launch_bounds__(512, 2) void fused_kernel(
    const float* __restrict__ x,
    const float* __restrict__ Gamma0, const float* __restrict__ Lambda0,
    const float* __restrict__ Lmid, const float* __restrict__ LambdaL,
    const float* __restrict__ F0W, const float* __restrict__ F0b,
    const float* __restrict__ FmidW, const float* __restrict__ Fmidb,
    const float* __restrict__ FlastW, const float* __restrict__ Flastb,
    const int* __restrict__ rstart, const int* __restrict__ perm,
    int* __restrict__ cnt, const _Float16* __restrict__ wsf,
    unsigned short* __restrict__ hb, float* __restrict__ out) {
    __shared__ FusedLds S;
    const int tid = threadIdx.x, lane = tid & 63, w = tid >> 6;

    for (;;) {
        __syncthreads();   // previous item's S reads complete before tkt/S overwrite
        if (tid == 0) S.tkt = atomicAdd(cnt, 1);
        __syncthreads();
        const int it = S.tkt;
        if (it >= BB) break;
        const int b = perm[it];            // heavy batches first (LPT)
        const int rs0 = rstart[b];
        if (rs0 >= M_CAP) continue;        // block-uniform
        const float* xb = x + (size_t)b * NN * FF;

        // ---- stage Gamma0; mask + compact x into LDS ----
        ((float4*)S.u.p.g0)[tid] = ((const float4*)Gamma0)[tid];
        ((float4*)S.u.p.g0)[tid + 512] = ((const float4*)Gamma0)[tid + 512];
        float4 v0, v1, v2, v3;
        bool flag = false;
        if (tid < NN) {
            const float4* xr = (const float4*)(xb + tid * FF);
            v0 = xr[0]; v1 = xr[1]; v2 = xr[2]; v3 = xr[3];
            flag = (v0.x != 0.f) | (v0.y != 0.f) | (v0.z != 0.f) | (v0.w != 0.f) |
                   (v1.x != 0.f) | (v1.y != 0.f) | (v1.z != 0.f) | (v1.w != 0.f) |
                   (v2.x != 0.f) | (v2.y != 0.f) | (v2.z != 0.f) | (v2.w != 0.f) |
                   (v3.x != 0.f) | (v3.y != 0.f) | (v3.z != 0.f) | (v3.w != 0.f);
        }
        unsigned long long bal = __ballot(flag);
        if (lane == 0) S.wavecnt[w] = __popcll(bal);
        {
            int n0 = tid >> 4, f = tid & 15;
            float a = 0.f;
            for (int n = n0; n < NN; n += 32) a += xb[n * FF + f];
            S.mred[n0 * 16 + f] = a;
        }
        __syncthreads();
        int basec = 0, tot = 0;
#pragma unroll
        for (int w2 = 0; w2 < 8; ++w2) {
            int c = S.wavecnt[w2];
            if (w2 < w) basec += c;
            tot += c;
        }
        const int Nv = min(tot, M_CAP - rs0);
        const float invNv = 1.0f / (float)Nv;
        if (flag) {
            int pos = basec + __popcll(bal & ((1ull << lane) - 1ull));
            float4* dst = (float4*)&S.u.p.xl[pos * FF];
            dst[0] = v0; dst[1] = v1; dst[2] = v2; dst[3] = v3;
        }
        if (tid < FF) {
            float s = 0.f;
#pragma unroll
            for (int g2 = 0; g2 < 32; ++g2) s += S.mred[g2 * 16 + tid];
            S.xmean[tid] = s * invNv;
        }
        __syncthreads();
        if (tid < WW) {
            float a = 0.f;
#pragma unroll
            for (int f = 0; f < FF; ++f) a = fmaf(S.xmean[f], Lambda0[f * WW + tid], a);
            S.mpj_s[tid] = a;
        }
        __syncthreads();

        // ---- layer 0 (K=16, fp32 VALU) + in-register colsum ----
        {
            const float4 mp = *(const float4*)&S.mpj_s[4 * lane];
            float p[4] = {0.f, 0.f, 0.f, 0.f};
            for (int r = w; r < Nv; r += 8) {
                float acc[4] = {0.f, 0.f, 0.f, 0.f};
#pragma unroll
                for (int f = 0; f < FF; ++f) {
                    float xv = S.u.p.xl[r * FF + f];
                    float4 gv = *(const float4*)&S.u.p.g0[f * WW + 4 * lane];
                    acc[0] = fmaf(xv, gv.x, acc[0]);
                    acc[1] = fmaf(xv, gv.y, acc[1]);
                    acc[2] = fmaf(xv, gv.z, acc[2]);
                    acc[3] = fmaf(xv, gv.w, acc[3]);
                }
                float o0 = lrelu(acc[0] - mp.x), o1 = lrelu(acc[1] - mp.y);
                float o2 = lrelu(acc[2] - mp.z), o3 = lrelu(acc[3] - mp.w);
                uint2 ov;
                ov.x = pk2(o0, o1);
                ov.y = pk2(o2, o3);
                *(uint2*)(hb + (size_t)(rs0 + r) * 256 + 4 * lane) = ov;
                p[0] += o0; p[1] += o1; p[2] += o2; p[3] += o3;
            }
            __syncthreads();   // xl/g0 dead after this (union may become stage tile)
#pragma unroll
            for (int c4 = 0; c4 < 4; ++c4) S.csred[w][4 * lane + c4] = p[c4];
            __syncthreads();
            if (tid < 256) {
                float s = 0.f;
#pragma unroll
                for (int w2 = 0; w2 < 8; ++w2) s += S.csred[w2][tid];
                S.csl[tid] = s;
            }
            __syncthreads();
        }

        if (Nv <= 128) {
            // ---- RESIDENT: load tile once; 4 layers LDS-only ----
            for (int l = 0; l < DD - 2; ++l) {
                mproj_mid(S, Lmid, l, invNv, tid);
                if (l == 0) {
                    tile_load(S, hb, rs0, Nv, tid);
                    __syncthreads();
                }
                eq_tile_res<256>(S, wsf + (size_t)l * 65536, Nv, tid, lane, w);
            }
            mproj_last(S, LambdaL, invNv, tid);
            eq_tile_res<128>(S, wsf + 196608, Nv, tid, lane, w);
        } else {
            // ---- MULTI-PASS: direct-global-gather layers ----
            for (int l = 0; l < DD - 2; ++l) {
                mproj_mid(S, Lmid, l, invNv, tid);
                gemm_layer<256>(S, wsf + (size_t)l * 65536, hb, rs0, Nv, tid, lane, w);
            }
            mproj_last(S, LambdaL, invNv, tid);
            gemm_layer<128>(S, wsf + 196608, hb, rs0, Nv, tid, lane, w);
        }

        // ---- MLP head (pooled = csl[0..128), unscaled) ----
        {
            const int c = tid & 255, seg = tid >> 8;
            float a = 0.f;
            const float* Wp = F0W + (size_t)seg * 64 * WW + c;
            const float* ip = S.csl + seg * 64;
#pragma unroll
            for (int k = 0; k < 64; ++k) a = fmaf(ip[k], Wp[(size_t)k * WW], a);
            S.mred[seg * WW + c] = a;
            __syncthreads();
            if (tid < WW) S.ybuf[0][tid] = lrelu(S.mred[tid] + S.mred[WW + tid] + F0b[tid]);
            __syncthreads();
        }
        int cur = 0;
        for (int i = 0; i < DD - 1; ++i) {
            const int c = tid & 255, seg = tid >> 8;
            const float* Wp = FmidW + (size_t)i * WW * WW + (size_t)seg * 128 * WW + c;
            const float* ip = S.ybuf[cur] + seg * 128;
            float a = 0.f;
#pragma unroll
            for (int k = 0; k < 128; ++k) a = fmaf(ip[k], Wp[(size_t)k * WW], a);
            S.mred[seg * WW + c] = a;
            __syncthreads();
            if (tid < WW)
                S.ybuf[1 - cur][tid] = lrelu(S.mred[tid] + S.mred[WW + tid] + Fmidb[i * WW + tid]);
            __syncthreads();
            cur = 1 - cur;
        }
        if (w == 0) {
            float s0 = 0.f, s1 = 0.f;
            for (int k = lane; k < WW; k += 64) {
                float yv = S.ybuf[cur][k];
                s0 = fmaf(yv, FlastW[2 * k], s0);
                s1 = fmaf(yv, FlastW[2 * k + 1], s1);
            }
#pragma unroll
            for (int off = 32; off > 0; off >>= 1) {
                s0 += __shfl_down(s0, off);
                s1 += __shfl_down(s1, off);
            }
            if (lane == 0) {
                s0 += Flastb[0];
                s1 += Flastb[1];
                float m = fmaxf(s0, s1);
                float e0 = expf(s0 - m), e1 = expf(s1 - m);
                float inv = 1.0f / (e0 + e1);
                out[2 * b] = e0 * inv;
                out[2 * b + 1] = e1 * inv;
            }
        }
    }
}

extern "C" void kernel_launch(void* const* d_in, const int* in_sizes, int n_in,
                              void* d_out, int out_size, void* d_ws, size_t ws_size,
                              hipStream_t stream) {
    const float* x = (const float*)d_in[0];
    const float* Gamma0 = (const float*)d_in[1];
    const float* Lambda0 = (const float*)d_in[2];
    const float* Gmid = (const float*)d_in[3];
    const float* Lmid = (const float*)d_in[4];
    const float* GammaL = (const float*)d_in[5];
    const float* LambdaL = (const float*)d_in[6];
    const float* F0W = (const float*)d_in[7];
    const float* F0b = (const float*)d_in[8];
    const float* FmidW = (const float*)d_in[9];
    const float* Fmidb = (const float*)d_in[10];
    const float* FlastW = (const float*)d_in[11];
    const float* Flastb = (const float*)d_in[12];
    float* out = (float*)d_out;

    int* cnt = (int*)((char*)d_ws + WS_CNT);
    int* nvb = (int*)((char*)d_ws + WS_NV);
    int* rstart = (int*)((char*)d_ws + WS_RS);
    int* perm = (int*)((char*)d_ws + WS_PERM);
    _Float16* wsf = (_Float16*)((char*)d_ws + WS_WSF);
    unsigned short* hb = (unsigned short*)((char*)d_ws + WS_H);

    k1_kernel<<<BB + 112, 256, 0, stream>>>(x, Gmid, GammaL, wsf, nvb);
    prefix_kernel<<<1, 512, 0, stream>>>(nvb, rstart, perm, cnt);
    fused_kernel<<<BB, 512, 0, stream>>>(x, Gamma0, Lambda0, Lmid, LambdaL,
                                         F0W, F0b, FmidW, Fmidb, FlastW, Flastb,
                                         rstart, perm, cnt, wsf, hb, out);
}

// Round 22
// 147.734 us; speedup vs baseline: 4.8291x; 4.8291x over previous
//
#include <hip/hip_runtime.h>
#include <hip/hip_fp16.h>
#include <stdint.h>

#define BB 512
#define NN 200
#define FF 16
#define WW 256
#define DD 5
#define LATD 128
#define ALPHA 0.2f

// ws layout (bytes)
#define WS_NV   0         // int nv[512]
#define WS_PERM 2048      // int perm[512] (rank -> batch, Nv descending)
#define WS_WSF  4096      // half wsf[229376] (Gmid frags l*65536; GammaL @196608)

typedef _Float16 f16x8 __attribute__((ext_vector_type(8)));
typedef float f32x4 __attribute__((ext_vector_type(4)));

__device__ __forceinline__ float lrelu(float v) { return v >= 0.f ? v : ALPHA * v; }
__device__ __forceinline__ unsigned pk2(float a, float b) {
    __half2 h = __floats2half2_rn(a, b);
    return *reinterpret_cast<unsigned*>(&h);
}
// swizzled tile byte offset: row-major 512B rows, XOR row bits into bits 4-6
__device__ __forceinline__ unsigned swz(int rl, int cb) {
    return (unsigned)(rl * 512 + cb) ^ (unsigned)((rl & 7) << 4);
}

// ---- K1: blocks [0,512): per-batch Nv; blocks [512,624): weight fragment packing ----
__global__ __launch_bounds__(256) void k1_kernel(const float* __restrict__ x,
                                                 const float* __restrict__ Gmid,
                                                 const float* __restrict__ GammaL,
                                                 _Float16* __restrict__ wsf,
                                                 int* __restrict__ nv) {
    const int tid = threadIdx.x;
    if (blockIdx.x < BB) {
        __shared__ int wavecnt[4];
        const int lane = tid & 63, w = tid >> 6;
        const float* xb = x + (size_t)blockIdx.x * NN * FF;
        bool flag = false;
        if (tid < NN) {
            const float4* xr = (const float4*)(xb + tid * FF);
            float4 v0 = xr[0], v1 = xr[1], v2 = xr[2], v3 = xr[3];
            flag = (v0.x != 0.f) | (v0.y != 0.f) | (v0.z != 0.f) | (v0.w != 0.f) |
                   (v1.x != 0.f) | (v1.y != 0.f) | (v1.z != 0.f) | (v1.w != 0.f) |
                   (v2.x != 0.f) | (v2.y != 0.f) | (v2.z != 0.f) | (v2.w != 0.f) |
                   (v3.x != 0.f) | (v3.y != 0.f) | (v3.z != 0.f) | (v3.w != 0.f);
        }
        unsigned long long bal = __ballot(flag);
        if (lane == 0) wavecnt[w] = __popcll(bal);
        __syncthreads();
        if (tid == 0) nv[blockIdx.x] = wavecnt[0] + wavecnt[1] + wavecnt[2] + wavecnt[3];
        return;
    }
    int t = (int)(blockIdx.x - BB) * 256 + tid;
    if (t < 24576) {                       // Gmid: 3 x (K=256 -> 32 octets) x (N=256)
        int layer = t / 8192, r = t % 8192;
        int a = r / 256, n = r % 256;
        const float* G = Gmid + (size_t)layer * 65536;
        f16x8 v;
#pragma unroll
        for (int j = 0; j < 8; ++j) v[j] = (_Float16)G[(8 * a + j) * 256 + n];
        int chunk = a >> 2, g = a & 3, cf = n >> 4, ln = (n & 15) + 16 * g;
        *(f16x8*)(wsf + (size_t)layer * 65536 + ((size_t)(chunk * 16 + cf) * 64 + ln) * 8) = v;
    } else if (t < 28672) {                // GammaL: K=256, N=128
        int r = t - 24576;
        int a = r / 128, n = r % 128;
        f16x8 v;
#pragma unroll
        for (int j = 0; j < 8; ++j) v[j] = (_Float16)GammaL[(8 * a + j) * 128 + n];
        int chunk = a >> 2, g = a & 3, cf = n >> 4, ln = (n & 15) + 16 * g;
        *(f16x8*)(wsf + 196608 + ((size_t)(chunk * 8 + cf) * 64 + ln) * 8) = v;
    }
}

// ---- K2: rank batches by Nv descending (deterministic) -> perm ----
__global__ __launch_bounds__(512) void rank_kernel(const int* __restrict__ nv,
                                                   int* __restrict__ perm) {
    __shared__ int nvs[512];
    const int t = threadIdx.x;
    int my = nv[t];
    nvs[t] = my;
    __syncthreads();
    int rank = 0;
    for (int b2 = 0; b2 < 512; ++b2) {
        int o = nvs[b2];
        rank += (o > my) || (o == my && b2 < t);
    }
    perm[rank] = t;
}

struct __align__(16) FusedLds {
    unsigned short tile[NN * 256]; // 102400 B swizzled h tile (whole batch resident)
    float xl[NN * FF];             // 12800 B compacted x
    float g0[FF * WW];             // 16384 B Gamma0
    float mred[512];               // 2048 B reduction scratch
    float csred[8][256];           // 8192 B per-wave colsum partials
    float csl[256];                // colsum / pooled
    float mpj_s[256];
    float ybuf[2][256];            // MLP ping-pong
    float xmean[FF];
    int wavecnt[8];
};                                  // ~146 KB (fits 160 KB; 1 block/CU)

// fs -> csl[0..NC)
template <int NC>
__device__ __forceinline__ void colsum_finish(FusedLds& S, const float* fs,
                                              int tid, int lane, int w) {
    constexpr int CPW = NC / 64;
    const int cg = w & 3, cl = lane & 15;
#pragma unroll
    for (int u = 0; u < CPW; ++u) {
        float s = fs[u];
        s += __shfl_xor(s, 16);
        s += __shfl_xor(s, 32);
        if (lane < 16) S.csred[w][(cg * CPW + u) * 16 + cl] = s;
    }
    __syncthreads();
    if (tid < NC) {
        const int cgb = tid / (16 * CPW);
        S.csl[tid] = S.csred[cgb][tid] + S.csred[4 + cgb][tid];
    }
    __syncthreads();
}

// RESIDENT layer, any Nv<=200: LDS-only, in-place on tile; up to 2 row-passes.
// CONSERVATIVE barriers: reads -> barrier -> guarded writes -> barrier per pass
// (round-21's barrier-free 2-pass variant was nondeterministic under graph replay).
template <int NC>
__device__ __forceinline__ void tile_layer(FusedLds& S, const _Float16* __restrict__ wf,
                                           int Nv, int tid, int lane, int w) {
    constexpr int CPW = NC / 64;
    const int rg = w >> 2, cg = w & 3, cl = lane & 15, g = lane >> 4;
    const int RFL = (Nv + 15) >> 4;        // <= 13
    float fs[CPW];
#pragma unroll
    for (int u = 0; u < CPW; ++u) fs[u] = 0.f;
    for (int p0 = 0; p0 < RFL; p0 += 8) {
        f32x4 acc[4][CPW];
#pragma unroll
        for (int i = 0; i < 4; ++i)
#pragma unroll
            for (int u = 0; u < CPW; ++u)
#pragma unroll
                for (int j = 0; j < 4; ++j) acc[i][u][j] = 0.f;
        bool act[4];
        int rll[4];
#pragma unroll
        for (int i = 0; i < 4; ++i) {
            const int rf = p0 + rg + 2 * i;
            act[i] = rf < RFL;
            int rl = rf * 16 + cl;
            rll[i] = rl < Nv ? rl : Nv - 1;   // clamped reads; writes guarded
        }
#pragma unroll
        for (int c = 0; c < 8; ++c) {
            f16x8 bfr[CPW];
#pragma unroll
            for (int u = 0; u < CPW; ++u)
                bfr[u] = *(const f16x8*)(wf + ((size_t)(c * (NC / 16) + cg * CPW + u) * 64 + lane) * 8);
#pragma unroll
            for (int i = 0; i < 4; ++i) {
                if (act[i]) {
                    f16x8 af = *(const f16x8*)((const char*)S.tile + swz(rll[i], c * 64 + (g << 4)));
#pragma unroll
                    for (int u = 0; u < CPW; ++u)
                        acc[i][u] = __builtin_amdgcn_mfma_f32_16x16x32_f16(af, bfr[u], acc[i][u], 0, 0, 0);
                }
            }
        }
        __syncthreads();   // all reads of old tile done before in-place writes
#pragma unroll
        for (int i = 0; i < 4; ++i) {
            if (act[i]) {
                const int rlb = (p0 + rg + 2 * i) * 16 + 4 * g;
#pragma unroll
                for (int j = 0; j < 4; ++j) {
                    const int rl = rlb + j;
                    if (rl < Nv) {
#pragma unroll
                        for (int u = 0; u < CPW; ++u) {
                            const int col = (cg * CPW + u) * 16 + cl;
                            float o = lrelu(acc[i][u][j] - S.mpj_s[col]);
                            *(_Float16*)((char*)S.tile + swz(rl, col * 2)) = (_Float16)o;
                            fs[u] += o;
                        }
                    }
                }
            }
        }
        __syncthreads();   // writes visible before next pass / next phase
    }
    colsum_finish<NC>(S, fs, tid, lane, w);
}

// mpj_s[0..256) = (csl @ Lmid[l]) * invNv
__device__ __forceinline__ void mproj_mid(FusedLds& S, const float* __restrict__ Lmid,
                                          int l, float invNv, int tid) {
    const float* L = Lmid + (size_t)l * 65536;
    const int c = tid & 255, seg = tid >> 8;
    float a = 0.f;
    const float* Lp = L + (size_t)seg * 128 * 256 + c;
    const float* mh = S.csl + seg * 128;
#pragma unroll 8
    for (int k = 0; k < 128; ++k) a = fmaf(mh[k], Lp[(size_t)k * 256], a);
    S.mred[seg * 256 + c] = a;
    __syncthreads();
    if (tid < 256) S.mpj_s[tid] = (S.mred[tid] + S.mred[256 + tid]) * invNv;
    __syncthreads();
}

// mpj_s[0..128) = (csl @ LambdaL) * invNv
__device__ __forceinline__ void mproj_last(FusedLds& S, const float* __restrict__ LambdaL,
                                           float invNv, int tid) {
    const int c = tid & 127, seg = tid >> 7;
    float a = 0.f;
    const float* Lp = LambdaL + (size_t)seg * 64 * 128 + c;
    const float* mh = S.csl + seg * 64;
#pragma unroll 8
    for (int k = 0; k < 64; ++k) a = fmaf(mh[k], Lp[(size_t)k * 128], a);
    S.mred[seg * 128 + c] = a;
    __syncthreads();
    if (tid < 128)
        S.mpj_s[tid] = (S.mred[tid] + S.mred[128 + tid] + S.mred[256 + tid] + S.mred[384 + tid]) * invNv;
    __syncthreads();
}

// ---- FUSED: one block per batch (LPT order), whole batch LDS-resident, no global h ----
__global__ __launch_bounds__(512, 2) void fused_kernel(
    const float* __restrict__ x,
    const float* __restrict__ Gamma0, const float* __restrict__ Lambda0,
    const float* __restrict__ Lmid, const float* __restrict__ LambdaL,
    const float* __restrict__ F0W, const float* __restrict__ F0b,
    const float* __restrict__ FmidW, const float* __restrict__ Fmidb,
    const float* __restrict__ FlastW, const float* __restrict__ Flastb,
    const int* __restrict__ perm, const _Float16* __restrict__ wsf,
    float* __restrict__ out) {
    __shared__ FusedLds S;
    const int tid = threadIdx.x, lane = tid & 63, w = tid >> 6;
    const int b = perm[blockIdx.x];   // heavy batches dispatched first (LPT)
    const float* xb = x + (size_t)b * NN * FF;

    // ---- stage Gamma0; mask + compact x into LDS ----
    ((float4*)S.g0)[tid] = ((const float4*)Gamma0)[tid];
    ((float4*)S.g0)[tid + 512] = ((const float4*)Gamma0)[tid + 512];
    float4 v0, v1, v2, v3;
    bool flag = false;
    if (tid < NN) {
        const float4* xr = (const float4*)(xb + tid * FF);
        v0 = xr[0]; v1 = xr[1]; v2 = xr[2]; v3 = xr[3];
        flag = (v0.x != 0.f) | (v0.y != 0.f) | (v0.z != 0.f) | (v0.w != 0.f) |
               (v1.x != 0.f) | (v1.y != 0.f) | (v1.z != 0.f) | (v1.w != 0.f) |
               (v2.x != 0.f) | (v2.y != 0.f) | (v2.z != 0.f) | (v2.w != 0.f) |
               (v3.x != 0.f) | (v3.y != 0.f) | (v3.z != 0.f) | (v3.w != 0.f);
    }
    unsigned long long bal = __ballot(flag);
    if (lane == 0) S.wavecnt[w] = __popcll(bal);
    // x column partial sums: 32 row-groups x 16 features -> mred[512]
    {
        int n0 = tid >> 4, f = tid & 15;
        float a = 0.f;
        for (int n = n0; n < NN; n += 32) a += xb[n * FF + f];
        S.mred[n0 * 16 + f] = a;
    }
    __syncthreads();
    int basec = 0, tot = 0;
#pragma unroll
    for (int w2 = 0; w2 < 8; ++w2) {
        int c = S.wavecnt[w2];
        if (w2 < w) basec += c;
        tot += c;
    }
    const int Nv = tot;                 // 1..200, always tile-resident
    const float invNv = 1.0f / (float)Nv;
    if (flag) {
        int pos = basec + __popcll(bal & ((1ull << lane) - 1ull));
        float4* dst = (float4*)&S.xl[pos * FF];
        dst[0] = v0; dst[1] = v1; dst[2] = v2; dst[3] = v3;
    }
    if (tid < FF) {
        float s = 0.f;
#pragma unroll
        for (int g2 = 0; g2 < 32; ++g2) s += S.mred[g2 * 16 + tid];
        S.xmean[tid] = s * invNv;
    }
    __syncthreads();
    // mpj0 = xmean @ Lambda0
    if (tid < WW) {
        float a = 0.f;
#pragma unroll
        for (int f = 0; f < FF; ++f) a = fmaf(S.xmean[f], Lambda0[f * WW + tid], a);
        S.mpj_s[tid] = a;
    }
    __syncthreads();

    // ---- layer 0 (K=16, fp32 VALU), writes swizzled tile + in-register colsum ----
    {
        const float4 mp = *(const float4*)&S.mpj_s[4 * lane];
        float p[4] = {0.f, 0.f, 0.f, 0.f};
        for (int r = w; r < Nv; r += 8) {
            float acc[4] = {0.f, 0.f, 0.f, 0.f};
#pragma unroll
            for (int f = 0; f < FF; ++f) {
                float xv = S.xl[r * FF + f];
                float4 gv = *(const float4*)&S.g0[f * WW + 4 * lane];
                acc[0] = fmaf(xv, gv.x, acc[0]);
                acc[1] = fmaf(xv, gv.y, acc[1]);
                acc[2] = fmaf(xv, gv.z, acc[2]);
                acc[3] = fmaf(xv, gv.w, acc[3]);
            }
            float o0 = lrelu(acc[0] - mp.x), o1 = lrelu(acc[1] - mp.y);
            float o2 = lrelu(acc[2] - mp.z), o3 = lrelu(acc[3] - mp.w);
            uint2 ov;
            ov.x = pk2(o0, o1);
            ov.y = pk2(o2, o3);
            *(uint2*)((char*)S.tile + swz(r, 8 * lane)) = ov;
            p[0] += o0; p[1] += o1; p[2] += o2; p[3] += o3;
        }
        __syncthreads();
#pragma unroll
        for (int c4 = 0; c4 < 4; ++c4) S.csred[w][4 * lane + c4] = p[c4];
        __syncthreads();
        if (tid < 256) {
            float s = 0.f;
#pragma unroll
            for (int w2 = 0; w2 < 8; ++w2) s += S.csred[w2][tid];
            S.csl[tid] = s;
        }
        __syncthreads();
    }

    // ---- 3 mid layers + last layer, all LDS-resident ----
    for (int l = 0; l < DD - 2; ++l) {
        mproj_mid(S, Lmid, l, invNv, tid);
        tile_layer<256>(S, wsf + (size_t)l * 65536, Nv, tid, lane, w);
    }
    mproj_last(S, LambdaL, invNv, tid);
    tile_layer<128>(S, wsf + 196608, Nv, tid, lane, w);

    // ---- MLP head (pooled = csl[0..128), unscaled) ----
    {
        const int c = tid & 255, seg = tid >> 8;
        float a = 0.f;
        const float* Wp = F0W + (size_t)seg * 64 * WW + c;
        const float* ip = S.csl + seg * 64;
#pragma unroll
        for (int k = 0; k < 64; ++k) a = fmaf(ip[k], Wp[(size_t)k * WW], a);
        S.mred[seg * WW + c] = a;
        __syncthreads();
        if (tid < WW) S.ybuf[0][tid] = lrelu(S.mred[tid] + S.mred[WW + tid] + F0b[tid]);
        __syncthreads();
    }
    int cur = 0;
    for (int i = 0; i < DD - 1; ++i) {
        const int c = tid & 255, seg = tid >> 8;
        const float* Wp = FmidW + (size_t)i * WW * WW + (size_t)seg * 128 * WW + c;
        const float* ip = S.ybuf[cur] + seg * 128;
        float a = 0.f;
#pragma unroll
        for (int k = 0; k < 128; ++k) a = fmaf(ip[k], Wp[(size_t)k * WW], a);
        S.mred[seg * WW + c] = a;
        __syncthreads();
        if (tid < WW)
            S.ybuf[1 - cur][tid] = lrelu(S.mred[tid] + S.mred[WW + tid] + Fmidb[i * WW + tid]);
        __syncthreads();
        cur = 1 - cur;
    }
    if (w == 0) {
        float s0 = 0.f, s1 = 0.f;
        for (int k = lane; k < WW; k += 64) {
            float yv = S.ybuf[cur][k];
            s0 = fmaf(yv, FlastW[2 * k], s0);
            s1 = fmaf(yv, FlastW[2 * k + 1], s1);
        }
#pragma unroll
        for (int off = 32; off > 0; off >>= 1) {
            s0 += __shfl_down(s0, off);
            s1 += __shfl_down(s1, off);
        }
        if (lane == 0) {
            s0 += Flastb[0];
            s1 += Flastb[1];
            float m = fmaxf(s0, s1);
            float e0 = expf(s0 - m), e1 = expf(s1 - m);
            float inv = 1.0f / (e0 + e1);
            out[2 * b] = e0 * inv;
            out[2 * b + 1] = e1 * inv;
        }
    }
}

extern "C" void kernel_launch(void* const* d_in, const int* in_sizes, int n_in,
                              void* d_out, int out_size, void* d_ws, size_t ws_size,
                              hipStream_t stream) {
    const float* x = (const float*)d_in[0];
    const float* Gamma0 = (const float*)d_in[1];
    const float* Lambda0 = (const float*)d_in[2];
    const float* Gmid = (const float*)d_in[3];
    const float* Lmid = (const float*)d_in[4];
    const float* GammaL = (const float*)d_in[5];
    const float* LambdaL = (const float*)d_in[6];
    const float* F0W = (const float*)d_in[7];
    const float* F0b = (const float*)d_in[8];
    const float* FmidW = (const float*)d_in[9];
    const float* Fmidb = (const float*)d_in[10];
    const float* FlastW = (const float*)d_in[11];
    const float* Flastb = (const float*)d_in[12];
    float* out = (float*)d_out;

    int* nvb = (int*)((char*)d_ws + WS_NV);
    int* perm = (int*)((char*)d_ws + WS_PERM);
    _Float16* wsf = (_Float16*)((char*)d_ws + WS_WSF);

    k1_kernel<<<BB + 112, 256, 0, stream>>>(x, Gmid, GammaL, wsf, nvb);
    rank_kernel<<<1, 512, 0, stream>>>(nvb, perm);
    fused_kernel<<<BB, 512, 0, stream>>>(x, Gamma0, Lambda0, Lmid, LambdaL,
                                         F0W, F0b, FmidW, Fmidb, FlastW, Flastb,
                                         perm, wsf, out);
}